// Round 3
// baseline (81.356 us; speedup 1.0000x reference)
//
#include <hip/hip_runtime.h>
#include <cstdint>

// ---------------------------------------------------------------------------
// JAX PRNG replication (verified bit-exact in rounds 1-2, absmax 0.0).
// key(42) -> threefry2x32 key (0,42), jax_threefry_partitionable semantics.
// ---------------------------------------------------------------------------
__host__ __device__ inline void threefry2x32(uint32_t k0, uint32_t k1,
                                             uint32_t x0, uint32_t x1,
                                             uint32_t& o0, uint32_t& o1) {
  const uint32_t ks2 = k0 ^ k1 ^ 0x1BD11BDAu;
  uint32_t v0 = x0 + k0, v1 = x1 + k1;
#define RL(v, r) (((v) << (r)) | ((v) >> (32 - (r))))
#define RND4(a, b, c, d)                                                       \
  v0 += v1; v1 = RL(v1, a); v1 ^= v0;                                          \
  v0 += v1; v1 = RL(v1, b); v1 ^= v0;                                          \
  v0 += v1; v1 = RL(v1, c); v1 ^= v0;                                          \
  v0 += v1; v1 = RL(v1, d); v1 ^= v0;
  RND4(13, 15, 26, 6)  v0 += k1;  v1 += ks2 + 1u;
  RND4(17, 29, 16, 24) v0 += ks2; v1 += k0 + 2u;
  RND4(13, 15, 26, 6)  v0 += k0;  v1 += k1 + 3u;
  RND4(17, 29, 16, 24) v0 += k1;  v1 += ks2 + 4u;
  RND4(13, 15, 26, 6)  v0 += ks2; v1 += k0 + 5u;
#undef RND4
#undef RL
  o0 = v0; o1 = v1;
}

#define IN_F 512
#define OUT_F 512
#define BATCH 512

// ---------------------------------------------------------------------------
// K1: mask generation — UNCHANGED (bit-exact verified, absmax 0.0).
// M[o][i] = selected ? 0.0f : 1e9f. Every row has >=1 selected edge, and
// x in [0,1), so min_i(x+mask) == min over selected i of x, bit-exact.
// ---------------------------------------------------------------------------
__global__ __launch_bounds__(512) void gen_mask_kernel(
    const float* __restrict__ pw, float* __restrict__ M,
    uint32_t kb0, uint32_t kb1, uint32_t kl0, uint32_t kl1) {
  const int o = blockIdx.x;
  const int i = threadIdx.x;

  const float2 w = ((const float2*)pw)[o * IN_F + i];
  const float mx = fmaxf(w.x, w.y);
  const float e0 = expf(w.x - mx);
  const float e1 = expf(w.y - mx);
  const float p = e1 / (e0 + e1);

  const uint32_t n = (uint32_t)(o * IN_F + i);
  uint32_t h0, h1;
  threefry2x32(kb0, kb1, 0u, n, h0, h1);
  const uint32_t bits = h0 ^ h1;
  const float u = __uint_as_float((bits >> 9) | 0x3F800000u) - 1.0f;
  const bool c = u < p;

  __shared__ unsigned long long words[8];
  __shared__ int cnt;
  if (i == 0) cnt = 0;
  __syncthreads();
  const unsigned long long bal = __ballot(c);
  if ((i & 63) == 0) {
    words[i >> 6] = bal;
    atomicAdd(&cnt, __popcll(bal));
  }
  __syncthreads();
  if (cnt == 0 && i == 0) {
    uint32_t c0, c1;
    threefry2x32(kl0, kl1, 0u, (uint32_t)o, c0, c1);
    const uint32_t rb = c0 ^ c1;
    const uint32_t col = rb & (IN_F - 1);
    words[col >> 6] |= (1ull << (col & 63u));
  }
  __syncthreads();
  const bool sel = (words[i >> 6] >> (i & 63)) & 1ull;
  M[o * IN_F + i] = sel ? 0.0f : 1e9f;
}

// ---------------------------------------------------------------------------
// K2: min-plus with SGPR-broadcast mask — no LDS/VMEM in the inner loop.
// lane = b (64 b per wave). m[o,k] is wave-uniform -> s_load into SGPRs
// (free VALU operand); x[b, k-chunk] held in 32 VGPRs per 32-k subchunk.
// Inner loop = exactly v_add + v_min per element (the 3.4 us VALU floor).
// Block 512 thr = 8 waves = 2 o-halves x 4 k-quarters; tile 64b x 16o;
// grid 8x32 = 256 blocks = 1 block/CU = 2 waves/SIMD. LDS only for the
// tiny 4-way k-quarter min combine. x loads are per-lane float4
// (uncoalesced across lanes but fully line-dense, L1-absorbed).
// ---------------------------------------------------------------------------
__global__ __launch_bounds__(512) void minplus_kernel(
    const float* __restrict__ x, const float* __restrict__ M,
    float* __restrict__ out) {
  const int tid = threadIdx.x;
  const int lane = tid & 63;
  const int wv = __builtin_amdgcn_readfirstlane(tid >> 6);  // 0..7, uniform
  const int oh = wv & 1;   // o-half (8 o's each)
  const int kq = wv >> 1;  // k-quarter (128 k each)
  const int b0 = blockIdx.x * 64;
  const int o0 = blockIdx.y * 16;
  const int kbase = kq * 128;
  const float* xrow = x + (size_t)(b0 + lane) * IN_F + kbase;

  float acc[8];
#pragma unroll
  for (int i = 0; i < 8; ++i) acc[i] = 1e30f;

#pragma unroll 1
  for (int ks = 0; ks < 4; ++ks) {  // 4 subchunks of 32 k
    float xr[32];
#pragma unroll
    for (int j = 0; j < 8; ++j) {
      const float4 v = *(const float4*)(xrow + ks * 32 + j * 4);
      xr[4 * j + 0] = v.x; xr[4 * j + 1] = v.y;
      xr[4 * j + 2] = v.z; xr[4 * j + 3] = v.w;
    }
#pragma unroll
    for (int oo = 0; oo < 8; ++oo) {
      // wave-uniform address -> s_load; SGPR operand is free in v_add
      const float* mp = M + (size_t)(o0 + oh * 8 + oo) * IN_F + kbase + ks * 32;
#pragma unroll
      for (int j = 0; j < 32; ++j)
        acc[oo] = fminf(acc[oo], xr[j] + mp[j]);
    }
  }

  // combine the 4 k-quarter partials (tiny LDS, padded stride 65)
  __shared__ float part[8][8][65];
#pragma unroll
  for (int oo = 0; oo < 8; ++oo) part[wv][oo][lane] = acc[oo];
  __syncthreads();

  const int o_loc = tid & 15;  // 0..15 -> 64B-contiguous stores
  const int brow = tid >> 4;   // 0..31
  const int oh2 = o_loc >> 3, oo2 = o_loc & 7;
#pragma unroll
  for (int ib = 0; ib < 2; ++ib) {
    const int bl = brow + ib * 32;
    float v = part[oh2][oo2][bl];
    v = fminf(v, part[2 + oh2][oo2][bl]);
    v = fminf(v, part[4 + oh2][oo2][bl]);
    v = fminf(v, part[6 + oh2][oo2][bl]);
    out[(size_t)(b0 + bl) * OUT_F + o0 + o_loc] = v;
  }
}

extern "C" void kernel_launch(void* const* d_in, const int* in_sizes, int n_in,
                              void* d_out, int out_size, void* d_ws, size_t ws_size,
                              hipStream_t stream) {
  (void)in_sizes; (void)n_in; (void)out_size; (void)ws_size;
  const float* x = (const float*)d_in[0];   // [512, 512]
  const float* pw = (const float*)d_in[1];  // [512, 512, 2]
  float* M = (float*)d_ws;                  // 1 MB
  float* out = (float*)d_out;

  uint32_t kb0, kb1, kf0, kf1, kl0, kl1;
  threefry2x32(0u, 42u, 0u, 0u, kb0, kb1);   // k_bern = hash(key; 0,0)
  threefry2x32(0u, 42u, 0u, 1u, kf0, kf1);   // k_fix  = hash(key; 0,1)
  threefry2x32(kf0, kf1, 0u, 1u, kl0, kl1);  // randint lower-bits key

  gen_mask_kernel<<<dim3(OUT_F), dim3(IN_F), 0, stream>>>(pw, M, kb0, kb1, kl0, kl1);
  minplus_kernel<<<dim3(BATCH / 64, OUT_F / 16), dim3(512), 0, stream>>>(x, M, out);
}

// Round 4
// 77.256 us; speedup vs baseline: 1.0531x; 1.0531x over previous
//
#include <hip/hip_runtime.h>
#include <cstdint>

// ---------------------------------------------------------------------------
// JAX PRNG replication (verified bit-exact rounds 1-3, absmax 0.0).
// key(42) -> threefry2x32 key (0,42), jax_threefry_partitionable semantics.
// ---------------------------------------------------------------------------
__host__ __device__ inline void threefry2x32(uint32_t k0, uint32_t k1,
                                             uint32_t x0, uint32_t x1,
                                             uint32_t& o0, uint32_t& o1) {
  const uint32_t ks2 = k0 ^ k1 ^ 0x1BD11BDAu;
  uint32_t v0 = x0 + k0, v1 = x1 + k1;
#define RL(v, r) (((v) << (r)) | ((v) >> (32 - (r))))
#define RND4(a, b, c, d)                                                       \
  v0 += v1; v1 = RL(v1, a); v1 ^= v0;                                          \
  v0 += v1; v1 = RL(v1, b); v1 ^= v0;                                          \
  v0 += v1; v1 = RL(v1, c); v1 ^= v0;                                          \
  v0 += v1; v1 = RL(v1, d); v1 ^= v0;
  RND4(13, 15, 26, 6)  v0 += k1;  v1 += ks2 + 1u;
  RND4(17, 29, 16, 24) v0 += ks2; v1 += k0 + 2u;
  RND4(13, 15, 26, 6)  v0 += k0;  v1 += k1 + 3u;
  RND4(17, 29, 16, 24) v0 += k1;  v1 += ks2 + 4u;
  RND4(13, 15, 26, 6)  v0 += ks2; v1 += k0 + 5u;
#undef RND4
#undef RL
  o0 = v0; o1 = v1;
}

#define IN_F 512
#define OUT_F 512
#define BATCH 512

// ---------------------------------------------------------------------------
// K1: mask generation — UNCHANGED (bit-exact verified, absmax 0.0).
// M[o][i] = selected ? 0.0f : 1e9f. Every row has >=1 selected edge and
// x in [0,1), so min_i(x+mask) == min over selected i of x, bit-exact.
// ---------------------------------------------------------------------------
__global__ __launch_bounds__(512) void gen_mask_kernel(
    const float* __restrict__ pw, float* __restrict__ M,
    uint32_t kb0, uint32_t kb1, uint32_t kl0, uint32_t kl1) {
  const int o = blockIdx.x;
  const int i = threadIdx.x;

  const float2 w = ((const float2*)pw)[o * IN_F + i];
  const float mx = fmaxf(w.x, w.y);
  const float e0 = expf(w.x - mx);
  const float e1 = expf(w.y - mx);
  const float p = e1 / (e0 + e1);

  const uint32_t n = (uint32_t)(o * IN_F + i);
  uint32_t h0, h1;
  threefry2x32(kb0, kb1, 0u, n, h0, h1);
  const uint32_t bits = h0 ^ h1;
  const float u = __uint_as_float((bits >> 9) | 0x3F800000u) - 1.0f;
  const bool c = u < p;

  __shared__ unsigned long long words[8];
  __shared__ int cnt;
  if (i == 0) cnt = 0;
  __syncthreads();
  const unsigned long long bal = __ballot(c);
  if ((i & 63) == 0) {
    words[i >> 6] = bal;
    atomicAdd(&cnt, __popcll(bal));
  }
  __syncthreads();
  if (cnt == 0 && i == 0) {
    uint32_t c0, c1;
    threefry2x32(kl0, kl1, 0u, (uint32_t)o, c0, c1);
    const uint32_t rb = c0 ^ c1;
    const uint32_t col = rb & (IN_F - 1);
    words[col >> 6] |= (1ull << (col & 63u));
  }
  __syncthreads();
  const bool sel = (words[i >> 6] >> (i & 63)) & 1ull;
  M[o * IN_F + i] = sel ? 0.0f : 1e9f;
}

// ---------------------------------------------------------------------------
// K2: min-plus, 4b x 4o register micro-tile (raises VALU:LDS ratio 8x over
// round 2's 2x1). Tile 64b x 64o x K=128, z-split 4 -> grid (8,8,4)=256
// blocks = 1/CU. Per k per wave: 2 ds_read_b128 (~22 LDS cy) feed 32 VALU.
// LDS rows stride 68 floats: 16B-aligned (b128-capable) and transpose-staging
// stores are only 4-way bank-aliased. Inner xv read: 16 distinct contiguous
// 16B addrs = conflict-free 2-phase; mv read: 4-addr broadcast.
// ---------------------------------------------------------------------------
#define BT 64
#define OT 64
#define KT 32
#define NZ 4
#define KZ (IN_F / NZ)  // 128

__global__ __launch_bounds__(256) void minplus_kernel(
    const float* __restrict__ x, const float* __restrict__ M,
    float* __restrict__ part) {
  __shared__ float xs[KT][BT + 4];  // [k][b], stride 68 (272 B, 16B-aligned)
  __shared__ float ms[KT][OT + 4];  // [k][o], stride 68

  const int tid = threadIdx.x;
  const int tx = tid & 15;   // b quad: b = b0 + 4*tx + i
  const int ty = tid >> 4;   // o quad: o = o0 + 4*ty + j   (0..15)
  const int b0 = blockIdx.x * BT;
  const int o0 = blockIdx.y * OT;
  const int kb = blockIdx.z * KZ;

  const int lr = tid >> 3;       // 0..31: staging row
  const int lc = (tid & 7) * 4;  // 0..28: staging k offset (float4)

  // acc[i] holds outputs for b = b0+4tx+i, o-quad in .x..w
  float4 acc[4];
#pragma unroll
  for (int i = 0; i < 4; ++i) acc[i] = make_float4(1e30f, 1e30f, 1e30f, 1e30f);

  for (int kt = 0; kt < KZ; kt += KT) {
    // stage x: 64 rows(b) x 32 cols(k); m: 64 rows(o) x 32 cols(k)
#pragma unroll
    for (int j = 0; j < 2; ++j) {
      const int r = j * 32 + lr;
      const float4 v = *(const float4*)&x[(b0 + r) * IN_F + kb + kt + lc];
      xs[lc + 0][r] = v.x; xs[lc + 1][r] = v.y;
      xs[lc + 2][r] = v.z; xs[lc + 3][r] = v.w;
      const float4 w = *(const float4*)&M[(o0 + r) * IN_F + kb + kt + lc];
      ms[lc + 0][r] = w.x; ms[lc + 1][r] = w.y;
      ms[lc + 2][r] = w.z; ms[lc + 3][r] = w.w;
    }
    __syncthreads();
#pragma unroll 8
    for (int k = 0; k < KT; ++k) {
      const float4 xv = *(const float4*)&xs[k][tx * 4];  // clean b128
      const float4 mv = *(const float4*)&ms[k][ty * 4];  // broadcast b128
#pragma unroll
      for (int i = 0; i < 4; ++i) {
        const float xi = (i == 0) ? xv.x : (i == 1) ? xv.y : (i == 2) ? xv.z : xv.w;
        acc[i].x = fminf(acc[i].x, xi + mv.x);
        acc[i].y = fminf(acc[i].y, xi + mv.y);
        acc[i].z = fminf(acc[i].z, xi + mv.z);
        acc[i].w = fminf(acc[i].w, xi + mv.w);
      }
    }
    __syncthreads();
  }

  float* pz = part + (size_t)blockIdx.z * (BATCH * OUT_F);
#pragma unroll
  for (int i = 0; i < 4; ++i)
    *(float4*)&pz[(size_t)(b0 + 4 * tx + i) * OUT_F + o0 + 4 * ty] = acc[i];
}

// ---------------------------------------------------------------------------
// K3: fold the NZ=4 k-slice partials (L2-resident, 4 MB) into d_out.
// ---------------------------------------------------------------------------
__global__ __launch_bounds__(256) void reduce_kernel(
    const float* __restrict__ part, float* __restrict__ out) {
  const int n = blockIdx.x * 256 + threadIdx.x;  // float4 index
  float4 a = ((const float4*)part)[n];
#pragma unroll
  for (int z = 1; z < NZ; ++z) {
    const float4 b = ((const float4*)(part + (size_t)z * BATCH * OUT_F))[n];
    a.x = fminf(a.x, b.x); a.y = fminf(a.y, b.y);
    a.z = fminf(a.z, b.z); a.w = fminf(a.w, b.w);
  }
  ((float4*)out)[n] = a;
}

extern "C" void kernel_launch(void* const* d_in, const int* in_sizes, int n_in,
                              void* d_out, int out_size, void* d_ws, size_t ws_size,
                              hipStream_t stream) {
  (void)in_sizes; (void)n_in; (void)out_size; (void)ws_size;
  const float* x = (const float*)d_in[0];   // [512, 512]
  const float* pw = (const float*)d_in[1];  // [512, 512, 2]
  float* M = (float*)d_ws;                            // 1 MB
  float* part = (float*)d_ws + BATCH * OUT_F;         // 4 MB (NZ=4 slices)
  float* out = (float*)d_out;

  uint32_t kb0, kb1, kf0, kf1, kl0, kl1;
  threefry2x32(0u, 42u, 0u, 0u, kb0, kb1);   // k_bern = hash(key; 0,0)
  threefry2x32(0u, 42u, 0u, 1u, kf0, kf1);   // k_fix  = hash(key; 0,1)
  threefry2x32(kf0, kf1, 0u, 1u, kl0, kl1);  // randint lower-bits key

  gen_mask_kernel<<<dim3(OUT_F), dim3(IN_F), 0, stream>>>(pw, M, kb0, kb1, kl0, kl1);
  minplus_kernel<<<dim3(BATCH / BT, OUT_F / OT, NZ), dim3(256), 0, stream>>>(x, M, part);
  reduce_kernel<<<dim3(BATCH * OUT_F / 4 / 256), dim3(256), 0, stream>>>(part, out);
}